// Round 7
// baseline (215.212 us; speedup 1.0000x reference)
//
#include <hip/hip_runtime.h>

#define NUM_USERS 200000
#define NUM_ITEMS 100000
#define NUM_NODES 300000
#define NUM_EDGES 600000
#define DIM      128
#define BATCH    16384
#define NSLOTS   (2 * BATCH)   // 32768 candidate slots
#define CAP      32            // max captured in-degree (Poisson(2): P(>32) ~ 1e-27)

typedef __attribute__((ext_vector_type(4))) float f32x4;
typedef __attribute__((ext_vector_type(8))) short bf16x8;

static __device__ __forceinline__ ushort f2bf(float x) {   // RNE, finite inputs
    unsigned u = __float_as_uint(x);
    return (ushort)((u + 0x7FFF + ((u >> 16) & 1)) >> 16);
}
static __device__ __forceinline__ float bf2f(ushort x) {
    return __uint_as_float(((unsigned)x) << 16);
}

// ---- K1 (fused): blocks 0-15: W->bf16. blocks 16+: zero cnt + build node->slot map.
__global__ __launch_bounds__(256) void init_misc(const float* __restrict__ W,
                                                 ushort* __restrict__ Wb,
                                                 const int* __restrict__ uidx,
                                                 const int* __restrict__ iidx,
                                                 int* __restrict__ map,
                                                 int* __restrict__ cnt) {
    int b = blockIdx.x;
    if (b < 16) {
        int t = b * 256 + threadIdx.x;             // 4096 threads x float4
        float4 v = ((const float4*)W)[t];
        ushort4 o = { f2bf(v.x), f2bf(v.y), f2bf(v.z), f2bf(v.w) };
        ((ushort4*)Wb)[t] = o;
    } else {
        int t = (b - 16) * 256 + threadIdx.x;
        if (t >= NSLOTS) return;
        cnt[t] = 0;                                // replaces the cnt memset dispatch
        int node = (t < BATCH) ? uidx[t] : (NUM_USERS + iidx[t - BATCH]);
        atomicCAS(&map[node], -1, t);              // map pre-set to -1 by memset 0xFF
    }
}

// ---- K2: bucket contributing edges by destination slot (one int atomic/edge). ----
__global__ void bin_edges(const int* __restrict__ edges, const int* __restrict__ map,
                          int* __restrict__ cnt, int* __restrict__ bucket) {
    int e = blockIdx.x * 256 + threadIdx.x;
    if (e >= NUM_EDGES) return;
    int dst = edges[NUM_EDGES + e];
    int s = map[dst];
    if (s < 0) return;                    // ~90% exit
    int src = edges[e];
    int p = atomicAdd(&cnt[s], 1);
    if (p < CAP) bucket[s * CAP + p] = src;
}

// ---- K3: gather. One wave per slot; exactly min(n,4) parallel row-loads. ----
// Wave-uniform n => the if(n>=k) guards are uniform branches; the k loads are
// independent and all issue before the first use (one memory latency total).
__global__ __launch_bounds__(256) void gather(const int* __restrict__ cnt,
                                              const int* __restrict__ bucket,
                                              const float* __restrict__ uemb,
                                              const float* __restrict__ iemb,
                                              ushort* __restrict__ aggb) {
    int s = blockIdx.x * 4 + (threadIdx.x >> 6);
    int lane = threadIdx.x & 63;
    int n = cnt[s]; if (n > CAP) n = CAP;
    const int* bk = bucket + s * CAP;

    float2 acc = {0.f, 0.f};
    float2 v0, v1, v2, v3;
    if (n >= 1) { int src = bk[0];
        const float* r = (src < NUM_USERS) ? uemb + (size_t)src * DIM
                                           : iemb + (size_t)(src - NUM_USERS) * DIM;
        v0 = ((const float2*)r)[lane]; }
    if (n >= 2) { int src = bk[1];
        const float* r = (src < NUM_USERS) ? uemb + (size_t)src * DIM
                                           : iemb + (size_t)(src - NUM_USERS) * DIM;
        v1 = ((const float2*)r)[lane]; }
    if (n >= 3) { int src = bk[2];
        const float* r = (src < NUM_USERS) ? uemb + (size_t)src * DIM
                                           : iemb + (size_t)(src - NUM_USERS) * DIM;
        v2 = ((const float2*)r)[lane]; }
    if (n >= 4) { int src = bk[3];
        const float* r = (src < NUM_USERS) ? uemb + (size_t)src * DIM
                                           : iemb + (size_t)(src - NUM_USERS) * DIM;
        v3 = ((const float2*)r)[lane]; }
    if (n >= 1) { acc.x += v0.x; acc.y += v0.y; }
    if (n >= 2) { acc.x += v1.x; acc.y += v1.y; }
    if (n >= 3) { acc.x += v2.x; acc.y += v2.y; }
    if (n >= 4) { acc.x += v3.x; acc.y += v3.y; }
    for (int k = 4; k < n; ++k) {                      // rare tail (P(n>4) ~ 5%)
        int src = bk[k];
        const float* r = (src < NUM_USERS) ? uemb + (size_t)src * DIM
                                           : iemb + (size_t)(src - NUM_USERS) * DIM;
        float2 t = ((const float2*)r)[lane];
        acc.x += t.x; acc.y += t.y;
    }
    ushort2 ob = { f2bf(acc.x), f2bf(acc.y) };
    ((ushort2*)(aggb + (size_t)s * DIM))[lane] = ob;
}

// ---- K4: transform via MFMA, j-split for occupancy. prop(bf16) = agg @ W^T + b ----
// 8192 waves (8/SIMD). A/B share the same (lane,elem)->k packing so internal
// k-permutation cancels; C/D: col=lane&15, row=(lane>>4)*4+reg (HW-verified).
__global__ __launch_bounds__(256) void transform_mfma(
        const ushort* __restrict__ aggb, const ushort* __restrict__ Wb,
        const float* __restrict__ bias, ushort* __restrict__ propb) {
    int gw = blockIdx.x * 4 + (threadIdx.x >> 6);   // global wave id, 0..8191
    int lane = threadIdx.x & 63;
    int stile = gw >> 2;                            // 0..2047: which 16 slots
    int jq = gw & 3;                                // 0..3: which 32 cols
    int lr = lane & 15, lg = lane >> 4;
    int s0 = stile * 16;

    f32x4 acc0 = {0.f, 0.f, 0.f, 0.f}, acc1 = {0.f, 0.f, 0.f, 0.f};
    const ushort* pa = aggb + (size_t)(s0 + lr) * DIM + lg * 8;
    const ushort* pw = Wb + (size_t)(jq * 32 + lr) * DIM + lg * 8;
#pragma unroll
    for (int ks = 0; ks < 4; ++ks) {
        bf16x8 af = *(const bf16x8*)(pa + ks * 32);
        bf16x8 w0 = *(const bf16x8*)(pw + ks * 32);
        bf16x8 w1 = *(const bf16x8*)(pw + 16 * DIM + ks * 32);
        acc0 = __builtin_amdgcn_mfma_f32_16x16x32_bf16(af, w0, acc0, 0, 0, 0);
        acc1 = __builtin_amdgcn_mfma_f32_16x16x32_bf16(af, w1, acc1, 0, 0, 0);
    }
    float b0 = bias[jq * 32 + lr], b1 = bias[jq * 32 + 16 + lr];
#pragma unroll
    for (int r = 0; r < 4; ++r) {
        size_t row = (size_t)(s0 + lg * 4 + r) * DIM;
        propb[row + jq * 32 + lr]      = f2bf(acc0[r] + b0);
        propb[row + jq * 32 + 16 + lr] = f2bf(acc1[r] + b1);
    }
}

// ---- K5: out[b] = dot(prop[slot(user)], prop[slot(item)]); one wave per output ----
__global__ void final_dot(const int* __restrict__ uidx, const int* __restrict__ iidx,
                          const int* __restrict__ map, const ushort* __restrict__ propb,
                          float* __restrict__ out) {
    int o = blockIdx.x * 4 + (threadIdx.x >> 6);
    if (o >= BATCH) return;
    int lane = threadIdx.x & 63;
    int su = map[uidx[o]];
    int si = map[NUM_USERS + iidx[o]];
    ushort2 a = ((const ushort2*)(propb + (size_t)su * DIM))[lane];
    ushort2 c = ((const ushort2*)(propb + (size_t)si * DIM))[lane];
    float v = bf2f(a.x) * bf2f(c.x) + bf2f(a.y) * bf2f(c.y);
#pragma unroll
    for (int off = 32; off > 0; off >>= 1) v += __shfl_down(v, off);
    if (lane == 0) out[o] = v;
}

extern "C" void kernel_launch(void* const* d_in, const int* in_sizes, int n_in,
                              void* d_out, int out_size, void* d_ws, size_t ws_size,
                              hipStream_t stream) {
    const int*   uidx  = (const int*)d_in[0];
    const int*   iidx  = (const int*)d_in[1];
    const float* uemb  = (const float*)d_in[2];
    const float* iemb  = (const float*)d_in[3];
    const float* W     = (const float*)d_in[4];
    const float* bias  = (const float*)d_in[5];
    const int*   edges = (const int*)d_in[6];
    float*       out   = (float*)d_out;

    char* ws = (char*)d_ws;
    int*    map    = (int*)ws;                         // 300000*4 = 1.2 MB
    int*    cnt    = (int*)(ws + (2u << 20));          // 128 KB
    int*    bucket = (int*)(ws + (3u << 20));          // 4 MB
    ushort* Wb     = (ushort*)(ws + (7u << 20));       // 32 KB
    ushort* aggb   = (ushort*)(ws + (8u << 20));       // 8 MB
    ushort* propb  = (ushort*)(ws + (16u << 20));      // 8 MB

    hipMemsetAsync(map, 0xFF, NUM_NODES * sizeof(int), stream);   // map = -1

    init_misc<<<16 + (NSLOTS + 255) / 256, 256, 0, stream>>>(W, Wb, uidx, iidx, map, cnt);
    bin_edges<<<(NUM_EDGES + 255) / 256, 256, 0, stream>>>(edges, map, cnt, bucket);
    gather<<<NSLOTS / 4, 256, 0, stream>>>(cnt, bucket, uemb, iemb, aggb);
    transform_mfma<<<NSLOTS / 16, 256, 0, stream>>>(aggb, Wb, bias, propb);
    final_dot<<<(BATCH + 3) / 4, 256, 0, stream>>>(uidx, iidx, map, propb, out);
}